// Round 1
// 626.120 us; speedup vs baseline: 1.0222x; 1.0222x over previous
//
#include <hip/hip_runtime.h>
#include <math.h>

#define BB 4
#define TT 10
#define NN 4096
#define HH 32
#define JP 144                    // padded j (132 real: 4 b * 33 kk)
#define NJ2 (NN*JP)               // 589824
#define NH (NN*HH)                // 131072
#define NPAIR (NN*NN/2)           // 8388608 (fp16 pairs / u32 words)

typedef __attribute__((ext_vector_type(8))) short short8;
typedef __attribute__((ext_vector_type(8))) _Float16 half8;
typedef __attribute__((ext_vector_type(4))) float floatx4;
typedef __attribute__((ext_vector_type(4))) unsigned int uintx4;
typedef __attribute__((ext_vector_type(2))) unsigned int uintx2;

__device__ inline unsigned short f2h(float f) {
    _Float16 h = (_Float16)f;                  // v_cvt_f16_f32, RNE
    unsigned short u; __builtin_memcpy(&u, &h, 2);
    return u;
}
__device__ inline unsigned pk2(float a, float b) {
    return (unsigned)f2h(a) | ((unsigned)f2h(b) << 16);
}

// ---------- prep: pack A_off=spl+I, A_on=off+dtw, A9=off+masked dtw+lap, thr u8 ----------
__global__ void k_pack(const float* __restrict__ dtw, const float* __restrict__ tdl,
                       const float* __restrict__ spl, const float* __restrict__ lap,
                       unsigned* __restrict__ Aoff, unsigned* __restrict__ Aon,
                       unsigned* __restrict__ A9, unsigned short* __restrict__ thr2) {
    int e = blockIdx.x * 256 + threadIdx.x;          // pair index
    if (e >= NPAIR) return;
    size_t gi = (size_t)e * 2;
    int row = (int)(gi >> 12);
    int c0 = (int)(gi & 4095);
    float2 d = ((const float2*)dtw)[e];
    float2 td = ((const float2*)tdl)[e];
    float2 s = ((const float2*)spl)[e];
    float2 l = ((const float2*)lap)[e];
    float td0 = ceilf(fabsf(td.x)), td1 = ceilf(fabsf(td.y));
    int th0 = 10 - (int)td0; if (th0 < 0) th0 = 0;
    int th1 = 10 - (int)td1; if (th1 < 0) th1 = 0;
    float off0 = s.x + ((row == c0) ? 1.f : 0.f);
    float off1 = s.y + ((row == c0 + 1) ? 1.f : 0.f);
    float on0 = off0 + d.x, on1 = off1 + d.y;
    // t=9 mask: t+1=10 > 10-td_c  <=>  td_c>0 ; plus dtw!=0 exactness
    float a90 = off0 + l.x + ((td0 > 0.f && d.x != 0.f) ? d.x : 0.f);
    float a91 = off1 + l.y + ((td1 > 0.f && d.y != 0.f) ? d.y : 0.f);
    Aoff[e] = pk2(off0, off1);
    Aon[e]  = pk2(on0, on1);
    A9[e]   = pk2(a90, a91);
    thr2[e] = (unsigned short)(th0 | (th1 << 8));
}

// ---------- zero the pad rows j in [132,144) of Ct (ws is poisoned every launch) ----------
__global__ void k_zpad(unsigned short* __restrict__ Ct) {
    int e = blockIdx.x * 256 + threadIdx.x;          // over 10*12*4096
    if (e >= TT * 12 * NN) return;
    int n = e & 4095;
    int r = e >> 12;
    int t = r / 12, j = 132 + (r % 12);
    Ct[(size_t)(t * JP + j) * NN + n] = 0;
}

// ---------- build Ct[t][j][n] fp16, scale folded; pass1 (h raw) ----------
__global__ void k_build_ct1(const float* __restrict__ inp, const float* __restrict__ st,
                            unsigned short* __restrict__ Ct) {
    int nb = blockIdx.x, b = blockIdx.y, t = blockIdx.z;
    int tid = threadIdx.x;
    float sc = (t == TT - 1) ? (1.f / 3.f) : 0.5f;
    int kk = tid & 31;          // channel 0..31 -> j = b*33 + 1 + kk
    int ng = tid >> 5;          // 0..7
    const float* stb = st + (size_t)(t * BB + b) * NH;
    unsigned short* crow = Ct + (size_t)(t * JP + b * 33 + 1 + kk) * NN;
    int n0 = nb * 128 + ng * 16;
#pragma unroll
    for (int i = 0; i < 16; i++) {
        int n = n0 + i;
        crow[n] = f2h(stb[n * 32 + kk] * sc);       // coalesced read across kk
    }
    if (tid < 128) {            // x row: j = b*33
        int n = nb * 128 + tid;
        Ct[(size_t)(t * JP + b * 33) * NN + n] = f2h(inp[((size_t)b * TT + t) * NN + n] * sc);
    }
}

// ---------- build Ct pass2: h replaced by r*h, r = sigmoid(gcn1 flat) ----------
__global__ void k_build_ct2(const float* __restrict__ inp, const float* __restrict__ st,
                            const float* __restrict__ G, unsigned short* __restrict__ Ct) {
    int nb = blockIdx.x, b = blockIdx.y, t = blockIdx.z;
    int tid = threadIdx.x;
    float sc = (t == TT - 1) ? (1.f / 3.f) : 0.5f;
    int kk = tid & 31;
    int ng = tid >> 5;
    const float* stb = st + (size_t)(t * BB + b) * NH;
    const float* Gb = G + (size_t)(t * BB + b) * NN * 64;   // flat index == jj
    unsigned short* crow = Ct + (size_t)(t * JP + b * 33 + 1 + kk) * NN;
    int n0 = nb * 128 + ng * 16;
#pragma unroll
    for (int i = 0; i < 16; i++) {
        int n = n0 + i;
        int jj = n * 32 + kk;
        float g = Gb[jj];
        float r = 1.0f / (1.0f + expf(-g));
        crow[n] = f2h(r * stb[jj] * sc);
    }
    if (tid < 128) {
        int n = nb * 128 + tid;
        Ct[(size_t)(t * JP + b * 33) * NN + n] = f2h(inp[((size_t)b * TT + t) * NN + n] * sc);
    }
}

// ---------- MFMA GEMM: Out[ks][t][m][j] = sum_{k in split} A_t[m,k] * C_t[k,j] ----------
// v2: register-prefetch pipeline + LDS double-buffer, ONE barrier per K-step.
// Global loads for step i+1 are issued during step i and stay in flight across the
// barrier (raw s_barrier + lgkmcnt(0)-only wait; __syncthreads would drain vmcnt(0)).
__global__ __launch_bounds__(256) void k_mfma(const unsigned* __restrict__ Aoff,
                                              const unsigned* __restrict__ Aon,
                                              const unsigned* __restrict__ A9,
                                              const unsigned short* __restrict__ thr2,
                                              const unsigned* __restrict__ Ct,
                                              float* __restrict__ Out) {
    int t = blockIdx.z;
    int ks = blockIdx.y;
    int m0 = blockIdx.x * 128;
    int k0 = ks * 2048;
    int tid = threadIdx.x;
    int w = tid >> 6, lane = tid & 63;
    int lm = lane & 15, q = lane >> 4;

    __shared__ short As[2][128 * 40];  // row stride 40 shorts (80B) dodges bank conflicts
    __shared__ short Cs[2][JP * 40];

    floatx4 acc[2][9];
#pragma unroll
    for (int i = 0; i < 2; i++)
#pragma unroll
        for (int j = 0; j < 9; j++) acc[i][j] = (floatx4){0.f, 0.f, 0.f, 0.f};

    const bool last = (t == TT - 1);

    // staging geometry: A = 128 rows x 16 u32 -> 512 uint4 items, 2/thread
    //                   C = 144 rows x 16 u32 -> 576 uint4 items, 2/thread (+1 for wave 0)
    const int arow0 = tid >> 2;              // 0..63
    const int arow1 = arow0 + 64;            // 64..127
    const int ac = (tid & 3) * 4;            // u32 col within row-chunk of 16
    const size_t kbase = (size_t)(k0 >> 1);  // u32 col base of this k-split
    const size_t ga0 = (size_t)(m0 + arow0) * 2048 + kbase + ac;
    const size_t ga1 = (size_t)(m0 + arow1) * 2048 + kbase + ac;
    const int cj0 = arow0;                   // 0..63
    const int cj1 = arow0 + 64;              // 64..127
    const int cj2 = arow0 + 128;             // 128..143 (wave 0 only)
    const unsigned* CtT = Ct + (size_t)t * JP * 2048 + kbase;

    // prefetch registers (loaded at step i, consumed at step i+1's write phase)
    uintx4 pO0, pO1, pA0, pA1, rC0, rC1, rC2;
    uintx2 pT0, pT1;

    auto LOADS = [&](int ku) {               // ku = u32 col offset within split
        if (last) {
            pO0 = *(const uintx4*)(A9 + ga0 + ku);
            pO1 = *(const uintx4*)(A9 + ga1 + ku);
        } else {
            pO0 = *(const uintx4*)(Aoff + ga0 + ku);
            pA0 = *(const uintx4*)(Aon  + ga0 + ku);
            pT0 = *(const uintx2*)(thr2 + ga0 + ku);
            pO1 = *(const uintx4*)(Aoff + ga1 + ku);
            pA1 = *(const uintx4*)(Aon  + ga1 + ku);
            pT1 = *(const uintx2*)(thr2 + ga1 + ku);
        }
        rC0 = *(const uintx4*)(CtT + (size_t)cj0 * 2048 + ku + ac);
        rC1 = *(const uintx4*)(CtT + (size_t)cj1 * 2048 + ku + ac);
        if (tid < 64) rC2 = *(const uintx4*)(CtT + (size_t)cj2 * 2048 + ku + ac);
    };

    auto SEL = [&](uintx4& dst, const uintx4& po, const uintx4& pa, const uintx2& pt) {
#pragma unroll
        for (int u = 0; u < 4; u++) {
            unsigned th = ((u < 2) ? pt[0] : pt[1]) >> ((u & 1) * 16);
            unsigned lo = ((int)(th & 255u) <= t) ? pa[u] : po[u];
            unsigned hi = ((int)((th >> 8) & 255u) <= t) ? pa[u] : po[u];
            dst[u] = (lo & 0xFFFFu) | (hi & 0xFFFF0000u);
        }
    };

    LOADS(0);                                // prologue: step 0 data
    int p = 0;
    for (int kb = 0; kb < 64; kb++) {
        // ---- write phase: select + stage into LDS buffer p (regs from step kb)
        short* Asb = As[p];
        short* Csb = Cs[p];
        unsigned* Asu = (unsigned*)Asb;
        unsigned* Csu = (unsigned*)Csb;
        uintx4 r0, r1;
        if (last) { r0 = pO0; r1 = pO1; }
        else { SEL(r0, pO0, pA0, pT0); SEL(r1, pO1, pA1, pT1); }
        *(uintx4*)(Asu + arow0 * 20 + ac) = r0;
        *(uintx4*)(Asu + arow1 * 20 + ac) = r1;
        *(uintx4*)(Csu + cj0 * 20 + ac) = rC0;
        *(uintx4*)(Csu + cj1 * 20 + ac) = rC1;
        if (tid < 64) *(uintx4*)(Csu + cj2 * 20 + ac) = rC2;
        // ---- issue next step's global loads; they stay in flight across the barrier
        if (kb < 63) LOADS((kb + 1) * 16);
        // ---- one barrier per step: wait own LDS writes only (NOT vmcnt)
        asm volatile("s_waitcnt lgkmcnt(0)" ::: "memory");
        __builtin_amdgcn_s_barrier();
        asm volatile("" ::: "memory");
        // ---- compute phase: fragments + MFMA from buffer p
        const short* Ab = Asb;
        const short* Cb = Csb;
        short8 a0v = *(const short8*)(Ab + (w * 32 + lm) * 40 + q * 8);
        short8 a1v = *(const short8*)(Ab + (w * 32 + 16 + lm) * 40 + q * 8);
        half8 ah0 = __builtin_bit_cast(half8, a0v);
        half8 ah1 = __builtin_bit_cast(half8, a1v);
#pragma unroll
        for (int jt = 0; jt < 9; jt++) {
            short8 bv = *(const short8*)(Cb + (jt * 16 + lm) * 40 + q * 8);
            half8 bh = __builtin_bit_cast(half8, bv);
            acc[0][jt] = __builtin_amdgcn_mfma_f32_16x16x32_f16(ah0, bh, acc[0][jt], 0, 0, 0);
            acc[1][jt] = __builtin_amdgcn_mfma_f32_16x16x32_f16(ah1, bh, acc[1][jt], 0, 0, 0);
        }
        p ^= 1;
        // no trailing barrier needed: next write targets the OTHER buffer; the
        // buffer written at step kb+2 was last read at step kb, and the step
        // kb+1 barrier orders those accesses for all waves.
    }
    // ---- epilogue: C/D layout col=lane&15, row=(lane>>4)*4+r
    float* Ob = Out + ((size_t)ks * TT + t) * (size_t)NN * JP;
#pragma unroll
    for (int mt = 0; mt < 2; mt++) {
        int row = m0 + w * 32 + mt * 16 + q * 4;
#pragma unroll
        for (int jt = 0; jt < 9; jt++) {
            int col = jt * 16 + lm;
#pragma unroll
            for (int r = 0; r < 4; r++)
                Ob[(size_t)(row + r) * JP + col] = acc[mt][jt][r];
        }
    }
}

// ---------- prefix sum over t (reads both k-splits, writes prefix into O0) ----------
__global__ void k_prefix(float* __restrict__ O0, const float* __restrict__ O1) {
    int e = blockIdx.x * 256 + threadIdx.x;
    if (e >= NJ2) return;
    float run = 0.f;
#pragma unroll
    for (int t = 0; t < TT; t++) {
        run += O0[(size_t)t * NJ2 + e] + O1[(size_t)t * NJ2 + e];
        O0[(size_t)t * NJ2 + e] = run;
    }
}

// ---------- gcn1[t][b][m][q] = (t+1)*b1[q] + sum_kk P[t][m][b*33+kk]*W1[kk][q] ----------
__global__ __launch_bounds__(256) void k_gcn1(const float* __restrict__ P,
                                              const float* __restrict__ W1,
                                              const float* __restrict__ b1,
                                              float* __restrict__ G) {
    int m0 = blockIdx.x * 32;
    int b = blockIdx.y, t = blockIdx.z;
    int tid = threadIdx.x;
    __shared__ float Ws[33 * 64];
    __shared__ float Ps[32 * 33];
    for (int l = tid; l < 33 * 64; l += 256) Ws[l] = W1[l];
    for (int l = tid; l < 32 * 33; l += 256) {
        int mr = l / 33, kk = l - mr * 33;
        Ps[l] = P[(size_t)(t * NN + m0 + mr) * JP + b * 33 + kk];
    }
    __syncthreads();
    int qq = tid & 63, ms = tid >> 6;
    float bias = (float)(t + 1) * b1[qq];
    for (int mi = 0; mi < 8; mi++) {
        int ml = ms * 8 + mi;
        float a = bias;
#pragma unroll
        for (int kk = 0; kk < 33; kk++) a = fmaf(Ps[ml * 33 + kk], Ws[kk * 64 + qq], a);
        G[(size_t)((t * BB + b) * NN + m0 + ml) * 64 + qq] = a;
    }
}

// ---------- reduce over t (both splits) -> S[m][JP] ----------
__global__ void k_reduce(const float* __restrict__ O0, const float* __restrict__ O1,
                         float* __restrict__ S) {
    int e = blockIdx.x * 256 + threadIdx.x;
    if (e >= NJ2) return;
    float s = 0.f;
#pragma unroll
    for (int t = 0; t < TT; t++)
        s += O0[(size_t)t * NJ2 + e] + O1[(size_t)t * NJ2 + e];
    S[e] = s;
}

// ---------- epilogue: gcn2@W2 + bias, tanh, u-gate ----------
__global__ __launch_bounds__(256) void k_final(const float* __restrict__ S,
                                               const float* __restrict__ G,
                                               const float* __restrict__ st,
                                               const float* __restrict__ W2,
                                               const float* __restrict__ b2,
                                               float* __restrict__ out) {
    __shared__ float Ws[33 * 32];
    int tid = threadIdx.x;
    for (int l = tid; l < 33 * 32; l += 256) Ws[l] = W2[l];
    __syncthreads();
    int e = blockIdx.x * 256 + tid;        // over B*N*H
    int b = e >> 17;
    int jj = e & (NH - 1);
    int m = jj >> 5, q = jj & 31;
    float a = 10.0f * b2[q];
#pragma unroll
    for (int kk = 0; kk < 33; kk++) a = fmaf(S[m * JP + b * 33 + kk], Ws[kk * 32 + q], a);
    float c = tanhf(a);
    float gu = G[(size_t)((9 * BB + b) * NN + 2048 + (jj >> 6)) * 64 + (jj & 63)];
    float u = 1.0f / (1.0f + expf(-gu));
    float h = st[(size_t)(9 * BB + b) * NH + jj];
    out[e] = u * h + (1.0f - u) * c;
}

extern "C" void kernel_launch(void* const* d_in, const int* in_sizes, int n_in,
                              void* d_out, int out_size, void* d_ws, size_t ws_size,
                              hipStream_t stream) {
    const float* inp = (const float*)d_in[0];
    const float* st  = (const float*)d_in[1];
    const float* dtw = (const float*)d_in[2];
    const float* spl = (const float*)d_in[3];
    const float* lap = (const float*)d_in[4];
    const float* tdl = (const float*)d_in[5];
    const float* W1  = (const float*)d_in[6];
    const float* b1  = (const float*)d_in[7];
    const float* W2  = (const float*)d_in[8];
    const float* b2  = (const float*)d_in[9];
    float* out = (float*)d_out;

    char* W = (char*)d_ws;
    unsigned*       Aoff = (unsigned*)W;                     W += (size_t)NPAIR * 4;
    unsigned*       Aon  = (unsigned*)W;                     W += (size_t)NPAIR * 4;
    unsigned*       A9   = (unsigned*)W;                     W += (size_t)NPAIR * 4;
    unsigned short* thr2 = (unsigned short*)W;               W += (size_t)NPAIR * 2;
    unsigned short* Ct   = (unsigned short*)W;               W += (size_t)TT * JP * NN * 2;
    float*          O    = (float*)W;                        W += (size_t)2 * TT * NJ2 * 4;
    float*          G    = (float*)W;                        W += (size_t)TT * BB * NN * 64 * 4;
    float*          S    = (float*)W;                        W += (size_t)NJ2 * 4;
    float* O1 = O + (size_t)TT * NJ2;

    k_pack<<<NPAIR / 256, 256, 0, stream>>>(dtw, tdl, spl, lap, Aoff, Aon, A9, thr2);
    k_zpad<<<(TT * 12 * NN + 255) / 256, 256, 0, stream>>>(Ct);

    dim3 gbld(NN / 128, BB, TT);
    k_build_ct1<<<gbld, 256, 0, stream>>>(inp, st, Ct);

    dim3 gmm(NN / 128, 2, TT);
    k_mfma<<<gmm, 256, 0, stream>>>(Aoff, Aon, A9, thr2, (const unsigned*)Ct, O);   // pass 1

    k_prefix<<<NJ2 / 256, 256, 0, stream>>>(O, O1);

    dim3 ggcn(NN / 32, BB, TT);
    k_gcn1<<<ggcn, 256, 0, stream>>>(O, W1, b1, G);

    k_build_ct2<<<gbld, 256, 0, stream>>>(inp, st, G, Ct);

    k_mfma<<<gmm, 256, 0, stream>>>(Aoff, Aon, A9, thr2, (const unsigned*)Ct, O);   // pass 2

    k_reduce<<<NJ2 / 256, 256, 0, stream>>>(O, O1, S);

    k_final<<<(BB * NN * HH) / 256, 256, 0, stream>>>(S, G, st, W2, b2, out);
}